// Round 2
// baseline (499.771 us; speedup 1.0000x reference)
//
#include <hip/hip_runtime.h>

typedef __bf16 bf16;
typedef __bf16 bf16x8 __attribute__((ext_vector_type(8)));
typedef __bf16 bf16x4 __attribute__((ext_vector_type(4)));
typedef float  f32x4  __attribute__((ext_vector_type(4)));

#define MFMA16(A,B,C) __builtin_amdgcn_mfma_f32_16x16x32_bf16(A,B,C,0,0,0)

static constexpr int BATCH = 2, HH = 112, WW = 112, CC = 192;
static constexpr int LL = HH*WW;              // 12544
static constexpr int NT = 784;                // tokens per window (112*7)
static constexpr float SCALE = 0.2041241452319315f;   // 24^-0.5

// ---------------- f32 -> bf16 weight conversion ----------------
__global__ __launch_bounds__(256) void cvt_kernel(const float* __restrict__ src,
                                                  bf16* __restrict__ dst, int n)
{
  int i = (blockIdx.x*256 + threadIdx.x)*4;
  if (i < n) {
    float4 v = *(const float4*)(src+i);
    bf16x4 o; o[0]=(bf16)v.x; o[1]=(bf16)v.y; o[2]=(bf16)v.z; o[3]=(bf16)v.w;
    *(bf16x4*)(dst+i) = o;
  }
}

// ---------------- LayerNorm over C=192, one wave per row ----------------
__global__ __launch_bounds__(256) void ln_kernel(const float* __restrict__ in,
    const float* __restrict__ w, const float* __restrict__ b, bf16* __restrict__ out)
{
  int row  = blockIdx.x*4 + (threadIdx.x>>6);
  int lane = threadIdx.x & 63;
  size_t base = (size_t)row*CC;
  float x0=in[base+lane], x1=in[base+lane+64], x2=in[base+lane+128];
  float s = x0+x1+x2;
  #pragma unroll
  for (int o=32;o>=1;o>>=1) s += __shfl_xor(s,o,64);
  float mu = s*(1.0f/CC);
  float d0=x0-mu,d1=x1-mu,d2=x2-mu;
  float v = d0*d0+d1*d1+d2*d2;
  #pragma unroll
  for (int o=32;o>=1;o>>=1) v += __shfl_xor(v,o,64);
  float rstd = rsqrtf(v*(1.0f/CC)+1e-5f);
  out[base+lane]     = (bf16)(d0*rstd*w[lane]     +b[lane]);
  out[base+lane+64]  = (bf16)(d1*rstd*w[lane+64]  +b[lane+64]);
  out[base+lane+128] = (bf16)(d2*rstd*w[lane+128] +b[lane+128]);
}

// ---------------- GEMM: out[M,N] = A[M,K] * W[N,K]^T (+epilogue) ----------------
// EPI 0: qkv (scale q cols<192, bf16 out), 1: proj(+bias + res_f32 -> f32)
// EPI 2: fc1(+bias + gelu, bf16 out),     3: fc2(+bias + res_f32 -> f32)
template<int EPI>
__global__ __launch_bounds__(256) void gemm_kernel(
    const bf16* __restrict__ A, const bf16* __restrict__ W, int K, int N,
    const float* __restrict__ bias, const float* __restrict__ resf,
    bf16* __restrict__ outb, float* __restrict__ outf)
{
  __shared__ __align__(16) bf16 As[64*72];
  __shared__ __align__(16) bf16 Bs[64*72];
  int m0 = blockIdx.x*64, n0 = blockIdx.y*64;
  int tid = threadIdx.x;
  int lane = tid&63, li = lane&15, quad = lane>>4;
  int wave = tid>>6, wm = wave>>1, wn = wave&1;
  int sr = tid>>2, sc = (tid&3)*8;
  f32x4 acc[2][2] = {};
  for (int k0 = 0; k0 < K; k0 += 64) {
    __syncthreads();
    const bf16* ga = A + (size_t)(m0+sr)*K + k0 + sc;
    const bf16* gb = W + (size_t)(n0+sr)*K + k0 + sc;
    *(bf16x8*)&As[sr*72+sc]    = *(const bf16x8*)ga;
    *(bf16x8*)&As[sr*72+sc+32] = *(const bf16x8*)(ga+32);
    *(bf16x8*)&Bs[sr*72+sc]    = *(const bf16x8*)gb;
    *(bf16x8*)&Bs[sr*72+sc+32] = *(const bf16x8*)(gb+32);
    __syncthreads();
    #pragma unroll
    for (int kk=0;kk<2;kk++){
      bf16x8 af0 = *(const bf16x8*)&As[(wm*32+li)*72   +kk*32+quad*8];
      bf16x8 af1 = *(const bf16x8*)&As[(wm*32+16+li)*72+kk*32+quad*8];
      bf16x8 bf0 = *(const bf16x8*)&Bs[(wn*32+li)*72   +kk*32+quad*8];
      bf16x8 bf1 = *(const bf16x8*)&Bs[(wn*32+16+li)*72+kk*32+quad*8];
      acc[0][0]=MFMA16(af0,bf0,acc[0][0]);
      acc[0][1]=MFMA16(af0,bf1,acc[0][1]);
      acc[1][0]=MFMA16(af1,bf0,acc[1][0]);
      acc[1][1]=MFMA16(af1,bf1,acc[1][1]);
    }
  }
  #pragma unroll
  for (int i=0;i<2;i++)
  #pragma unroll
  for (int j=0;j<2;j++){
    int col = n0 + wn*32 + j*16 + li;
    float bv = (EPI==0) ? 0.0f : bias[col];
    #pragma unroll
    for (int r=0;r<4;r++){
      int row = m0 + wm*32 + i*16 + quad*4 + r;
      float v = acc[i][j][r] + bv;
      size_t off = (size_t)row*N + col;
      if (EPI==0)      { if (col < CC) v *= SCALE; outb[off] = (bf16)v; }
      else if (EPI==2) { v = 0.5f*v*(1.0f+erff(v*0.70710678118654752f)); outb[off] = (bf16)v; }
      else             { v += resf[off]; outf[off] = v; }
    }
  }
}

// ---------------- position-bias MLP (tiny) ----------------
__device__ __forceinline__ void ln6_relu(float* v, const float* w, const float* b){
  float mu=0;
  #pragma unroll
  for (int i=0;i<6;i++) mu += v[i];
  mu *= (1.0f/6.0f);
  float var=0;
  #pragma unroll
  for (int i=0;i<6;i++){ float d=v[i]-mu; var += d*d; }
  var *= (1.0f/6.0f);
  float rstd = rsqrtf(var + 1e-5f);
  #pragma unroll
  for (int i=0;i<6;i++){ float t=(v[i]-mu)*rstd*w[i]+b[i]; v[i] = t>0.f? t:0.f; }
}
__device__ __forceinline__ void fc66(const float* in, float* out, const float* w, const float* b){
  #pragma unroll
  for (int i=0;i<6;i++){
    float s=b[i];
    #pragma unroll
    for (int j=0;j<6;j++) s += in[j]*w[i*6+j];
    out[i]=s;
  }
}
__global__ __launch_bounds__(256) void pos_mlp_kernel(
    const float* pw, const float* pb, const float* l1w, const float* l1b,
    const float* f1w, const float* f1b, const float* l2w, const float* l2b,
    const float* f2w, const float* f2b, const float* l3w, const float* l3b,
    const float* f3w, const float* f3b, float* __restrict__ posb)
{
  int gid = blockIdx.x*256 + threadIdx.x;
  if (gid >= 2*2899) return;
  int br = gid / 2899, r = gid % 2899;
  int Hsp = br? 7:112, Wsp = br?112:7;
  int lpw = 2*Wsp-1;
  int iph = r / lpw, ipw = r % lpw;
  float c0 = (float)(iph - (Hsp-1)), c1 = (float)(ipw - (Wsp-1));
  float v[6], t[6];
  #pragma unroll
  for (int i=0;i<6;i++)
    v[i] = c0*pw[br*12+i*2] + c1*pw[br*12+i*2+1] + pb[br*6+i];
  ln6_relu(v, l1w+br*6, l1b+br*6); fc66(v, t, f1w+br*36, f1b+br*6);
  ln6_relu(t, l2w+br*6, l2b+br*6); fc66(t, v, f2w+br*36, f2b+br*6);
  ln6_relu(v, l3w+br*6, l3b+br*6);
  #pragma unroll
  for (int h=0;h<4;h++){
    float s=f3b[br*4+h];
    #pragma unroll
    for (int j=0;j<6;j++) s += v[j]*f3w[br*24+h*6+j];
    posb[(size_t)(br*2899 + r)*4 + h] = s;
  }
}

// ---------------- expand bias table -> rpb[br][h][j][i] (bf16, transposed) ----------------
__global__ __launch_bounds__(256) void rpb_kernel(const float* __restrict__ posb,
                                                  bf16* __restrict__ rpb)
{
  int bid = blockIdx.x;                 // (br*4+h)*784 + j
  int brh = bid / NT, j = bid % NT;
  int br = brh >> 2, h = brh & 3;
  int Hsp = br?7:112, Wsp = br?112:7, lpw = 2*Wsp-1;
  int rhj, rwj;
  if (br==0) { rhj = j/7; rwj = j - rhj*7; } else { rhj = j/112; rwj = j - rhj*112; }
  const float* pbt = posb + (size_t)br*2899*4;
  bf16* dst = rpb + (size_t)bid*NT;
  for (int i = threadIdx.x; i < NT; i += 256) {
    int rhi, rwi;
    if (br==0) { rhi = i/7; rwi = i - rhi*7; } else { rhi = i/112; rwi = i - rhi*112; }
    int idx = (rhi - rhj + Hsp-1)*lpw + (rwi - rwj + Wsp-1);
    dst[i] = (bf16)pbt[idx*4 + h];
  }
}

// ---------------- flash attention, one block per (br,b,window,head) ----------------
__device__ __forceinline__ int tok2l(int br, int t, int w) {
  if (br == 0) return (t/7)*WW + w*7 + (t - (t/7)*7);
  int th = t/112; return (w*7 + th)*WW + (t - th*112);
}

__global__ __launch_bounds__(512) void attn_kernel(const bf16* __restrict__ qkv,
    const bf16* __restrict__ rpb, bf16* __restrict__ out)
{
  __shared__ __align__(16) bf16 Ks[832*40];    // [key 832][d 40], d>=24 zero
  __shared__ __align__(16) bf16 Vt[32*840];    // [d 32][key 840], row 24 = ones
  __shared__ __align__(16) bf16 Ps[8][32*72];  // per-wave P [i 32][key 72]
  int bid = blockIdx.x;
  int br = bid & 1, h = (bid>>1)&3, w = (bid>>3)&15, b = bid>>7;  // (br,h) -> XCD
  int tid = threadIdx.x;
  int lane = tid&63, li = lane&15, quad = lane>>4, wave = tid>>6;
  size_t qbase = (size_t)b*LL*576;
  int coff = br*96 + h*24;
  // zero LDS (pads)
  for (int c = tid; c < (832*40)/8; c += 512) ((int4*)Ks)[c] = make_int4(0,0,0,0);
  for (int c = tid; c < (32*840)/8; c += 512) ((int4*)Vt)[c] = make_int4(0,0,0,0);
  __syncthreads();
  // stage K
  for (int c = tid; c < NT*3; c += 512) {
    int j = c/3, p = c - j*3;
    int l = tok2l(br, j, w);
    *(bf16x8*)&Ks[j*40 + p*8] =
        *(const bf16x8*)(qkv + qbase + (size_t)l*576 + 192 + coff + p*8);
  }
  // stage V transposed + ones row (softmax denominator via MFMA)
  for (int j = tid; j < NT; j += 512) {
    int l = tok2l(br, j, w);
    const bf16* src = qkv + qbase + (size_t)l*576 + 384 + coff;
    bf16x8 v0 = *(const bf16x8*)src;
    bf16x8 v1 = *(const bf16x8*)(src+8);
    bf16x8 v2 = *(const bf16x8*)(src+16);
    #pragma unroll
    for (int d=0; d<8; d++){
      Vt[d*840 + j]      = v0[d];
      Vt[(8+d)*840 + j]  = v1[d];
      Vt[(16+d)*840 + j] = v2[d];
    }
    Vt[24*840 + j] = (bf16)1.0f;
  }
  __syncthreads();
  const bf16* rpbh = rpb + (size_t)(br*4 + h)*NT*NT;
  for (int qg = wave; qg < 25; qg += 8) {      // 32 q-rows per group
    bf16x8 qf[2]; int iu[2];
    #pragma unroll
    for (int t=0;t<2;t++){
      iu[t] = qg*32 + t*16 + li;
      int ic = iu[t] < NT ? iu[t] : NT-1;
      int l = tok2l(br, ic, w);
      qf[t] = *(const bf16x8*)(qkv + qbase + (size_t)l*576 + coff + quad*8);
    }
    int icol0 = iu[0] < NT ? iu[0] : NT-1;
    int icol1 = iu[1] < NT ? iu[1] : NT-1;
    f32x4 O[2][2] = {};
    float m0 = -3e38f, m1 = -3e38f;
    for (int kc = 0; kc < 13; kc++) {          // 64 keys per chunk
      int kb = kc*64;
      bf16x8 kf[4];
      #pragma unroll
      for (int kt=0;kt<4;kt++)
        kf[kt] = *(const bf16x8*)&Ks[(kb + kt*16 + li)*40 + quad*8];
      f32x4 S[2][4];
      #pragma unroll
      for (int kt=0;kt<4;kt++){
        #pragma unroll
        for (int r=0;r<4;r++){
          int j = kb + kt*16 + quad*4 + r;
          float bv0 = (j < NT) ? (float)rpbh[(size_t)j*NT + icol0] : -1e30f;
          float bv1 = (j < NT) ? (float)rpbh[(size_t)j*NT + icol1] : -1e30f;
          S[0][kt][r] = bv0; S[1][kt][r] = bv1;
        }
      }
      #pragma unroll
      for (int kt=0;kt<4;kt++){
        S[0][kt] = MFMA16(kf[kt], qf[0], S[0][kt]);   // S^T = K*Q^T + bias^T
        S[1][kt] = MFMA16(kf[kt], qf[1], S[1][kt]);
      }
      #pragma unroll
      for (int qt=0;qt<2;qt++){
        float& mm = qt ? m1 : m0;
        f32x4* Sq = S[qt];
        float mx = Sq[0][0];
        #pragma unroll
        for (int kt=0;kt<4;kt++)
          #pragma unroll
          for (int r=0;r<4;r++) mx = fmaxf(mx, Sq[kt][r]);
        mx = fmaxf(mx, __shfl_xor(mx,16,64));
        mx = fmaxf(mx, __shfl_xor(mx,32,64));
        float mnew = fmaxf(mm, mx);
        float alpha = __expf(mm - mnew);
        mm = mnew;
        #pragma unroll
        for (int dt=0;dt<2;dt++)
          #pragma unroll
          for (int r=0;r<4;r++) O[qt][dt][r] *= alpha;
        #pragma unroll
        for (int kt=0;kt<4;kt++){
          bf16x4 p4;
          #pragma unroll
          for (int r=0;r<4;r++) p4[r] = (bf16)__expf(Sq[kt][r] - mnew);
          *(bf16x4*)&Ps[wave][(qt*16+li)*72 + kt*16 + quad*4] = p4;
        }
      }
      asm volatile("s_waitcnt lgkmcnt(0)" ::: "memory");
      #pragma unroll
      for (int kk=0;kk<2;kk++){
        bf16x8 pf0 = *(const bf16x8*)&Ps[wave][li*72      + kk*32 + quad*8];
        bf16x8 pf1 = *(const bf16x8*)&Ps[wave][(16+li)*72 + kk*32 + quad*8];
        #pragma unroll
        for (int dt=0;dt<2;dt++){
          bf16x8 vf = *(const bf16x8*)&Vt[(dt*16+li)*840 + kb + kk*32 + quad*8];
          O[0][dt] = MFMA16(vf, pf0, O[0][dt]);       // O^T = Vt * P^T
          O[1][dt] = MFMA16(vf, pf1, O[1][dt]);
        }
      }
    }
    #pragma unroll
    for (int qt=0;qt<2;qt++){
      float lsum = __shfl(O[qt][1][0], 32+li, 64);    // ones-row (d=24) holds l_i
      float inv = 1.0f/lsum;
      int ii = iu[qt];
      if (ii < NT) {
        int l = tok2l(br, ii, w);
        bf16* dst = out + ((size_t)(b*LL + l))*CC + coff;
        #pragma unroll
        for (int dt=0;dt<2;dt++)
          #pragma unroll
          for (int r=0;r<4;r++){
            int d = dt*16 + quad*4 + r;
            if (d < 24) dst[d] = (bf16)(O[qt][dt][r]*inv);
          }
      }
    }
  }
}

// ---------------- host launcher ----------------
extern "C" void kernel_launch(void* const* d_in, const int* in_sizes, int n_in,
                              void* d_out, int out_size, void* d_ws, size_t ws_size,
                              hipStream_t stream)
{
  const float* x    = (const float*)d_in[0];
  const float* n1w  = (const float*)d_in[1];
  const float* n1b  = (const float*)d_in[2];
  const float* qkvw = (const float*)d_in[3];
  const float* pjw  = (const float*)d_in[4];
  const float* pjb  = (const float*)d_in[5];
  const float* n2w  = (const float*)d_in[6];
  const float* n2b  = (const float*)d_in[7];
  const float* f1w  = (const float*)d_in[8];
  const float* f1b  = (const float*)d_in[9];
  const float* f2w  = (const float*)d_in[10];
  const float* f2b  = (const float*)d_in[11];

  char* p = (char*)d_ws;
  auto alloc = [&](size_t bytes){ void* r = (void*)p; p += (bytes + 255) & ~(size_t)255; return r; };
  bf16*  img  = (bf16*) alloc((size_t)25088*192*2);
  bf16*  qkvb = (bf16*) alloc((size_t)25088*576*2);
  bf16*  attn = (bf16*) alloc((size_t)25088*192*2);
  float* x2   = (float*)alloc((size_t)25088*192*4);
  bf16*  y    = (bf16*) alloc((size_t)25088*192*2);
  bf16*  hbuf = (bf16*) alloc((size_t)25088*768*2);
  float* posb = (float*)alloc((size_t)2*2899*4*4);
  bf16*  rpbb = (bf16*) alloc((size_t)2*4*784*784*2);
  bf16*  qkvw_b = (bf16*)alloc((size_t)576*192*2);
  bf16*  pjw_b  = (bf16*)alloc((size_t)192*192*2);
  bf16*  f1w_b  = (bf16*)alloc((size_t)768*192*2);
  bf16*  f2w_b  = (bf16*)alloc((size_t)192*768*2);
  float* outp = (float*)d_out;

  cvt_kernel<<<108,256,0,stream>>>(qkvw, qkvw_b, 576*192);
  cvt_kernel<<<36, 256,0,stream>>>(pjw,  pjw_b,  192*192);
  cvt_kernel<<<144,256,0,stream>>>(f1w,  f1w_b,  768*192);
  cvt_kernel<<<144,256,0,stream>>>(f2w,  f2w_b,  192*768);

  ln_kernel<<<6272,256,0,stream>>>(x, n1w, n1b, img);
  gemm_kernel<0><<<dim3(392,9),256,0,stream>>>(img, qkvw_b, 192, 576,
      nullptr, nullptr, qkvb, nullptr);
  pos_mlp_kernel<<<23,256,0,stream>>>(
      (const float*)d_in[12], (const float*)d_in[13], (const float*)d_in[14],
      (const float*)d_in[15], (const float*)d_in[16], (const float*)d_in[17],
      (const float*)d_in[18], (const float*)d_in[19], (const float*)d_in[20],
      (const float*)d_in[21], (const float*)d_in[22], (const float*)d_in[23],
      (const float*)d_in[24], (const float*)d_in[25], posb);
  rpb_kernel<<<6272,256,0,stream>>>(posb, rpbb);
  attn_kernel<<<256,512,0,stream>>>(qkvb, rpbb, attn);
  gemm_kernel<1><<<dim3(392,3),256,0,stream>>>(attn, pjw_b, 192, 192,
      pjb, x, nullptr, x2);
  ln_kernel<<<6272,256,0,stream>>>(x2, n2w, n2b, y);
  gemm_kernel<2><<<dim3(392,12),256,0,stream>>>(y, f1w_b, 192, 768,
      f1b, nullptr, hbuf, nullptr);
  gemm_kernel<3><<<dim3(392,3),256,0,stream>>>(hbuf, f2w_b, 768, 192,
      f2b, x2, nullptr, outp);
}

// Round 3
// 305.364 us; speedup vs baseline: 1.6366x; 1.6366x over previous
//
#include <hip/hip_runtime.h>

typedef __bf16 bf16;
typedef __bf16 bf16x8 __attribute__((ext_vector_type(8)));
typedef __bf16 bf16x4 __attribute__((ext_vector_type(4)));
typedef float  f32x4  __attribute__((ext_vector_type(4)));

#define MFMA16(A,B,C) __builtin_amdgcn_mfma_f32_16x16x32_bf16(A,B,C,0,0,0)

static constexpr int BATCH = 2, HH = 112, WW = 112, CC = 192;
static constexpr int LL = HH*WW;              // 12544
static constexpr int NT = 784;                // tokens per window (112*7)
static constexpr float SCALE = 0.2041241452319315f;   // 24^-0.5

// ---------------- f32 -> bf16 weight conversion ----------------
__global__ __launch_bounds__(256) void cvt_kernel(const float* __restrict__ src,
                                                  bf16* __restrict__ dst, int n)
{
  int i = (blockIdx.x*256 + threadIdx.x)*4;
  if (i < n) {
    float4 v = *(const float4*)(src+i);
    bf16x4 o; o[0]=(bf16)v.x; o[1]=(bf16)v.y; o[2]=(bf16)v.z; o[3]=(bf16)v.w;
    *(bf16x4*)(dst+i) = o;
  }
}

// ---------------- LayerNorm over C=192, one wave per row ----------------
__global__ __launch_bounds__(256) void ln_kernel(const float* __restrict__ in,
    const float* __restrict__ w, const float* __restrict__ b, bf16* __restrict__ out)
{
  int row  = blockIdx.x*4 + (threadIdx.x>>6);
  int lane = threadIdx.x & 63;
  size_t base = (size_t)row*CC;
  float x0=in[base+lane], x1=in[base+lane+64], x2=in[base+lane+128];
  float s = x0+x1+x2;
  #pragma unroll
  for (int o=32;o>=1;o>>=1) s += __shfl_xor(s,o,64);
  float mu = s*(1.0f/CC);
  float d0=x0-mu,d1=x1-mu,d2=x2-mu;
  float v = d0*d0+d1*d1+d2*d2;
  #pragma unroll
  for (int o=32;o>=1;o>>=1) v += __shfl_xor(v,o,64);
  float rstd = rsqrtf(v*(1.0f/CC)+1e-5f);
  out[base+lane]     = (bf16)(d0*rstd*w[lane]     +b[lane]);
  out[base+lane+64]  = (bf16)(d1*rstd*w[lane+64]  +b[lane+64]);
  out[base+lane+128] = (bf16)(d2*rstd*w[lane+128] +b[lane+128]);
}

// ---------------- GEMM: out[M,N] = A[M,K] * W[N,K]^T (+epilogue) ----------------
template<int EPI>
__global__ __launch_bounds__(256) void gemm_kernel(
    const bf16* __restrict__ A, const bf16* __restrict__ W, int K, int N,
    const float* __restrict__ bias, const float* __restrict__ resf,
    bf16* __restrict__ outb, float* __restrict__ outf)
{
  __shared__ __align__(16) bf16 As[64*72];
  __shared__ __align__(16) bf16 Bs[64*72];
  int m0 = blockIdx.x*64, n0 = blockIdx.y*64;
  int tid = threadIdx.x;
  int lane = tid&63, li = lane&15, quad = lane>>4;
  int wave = tid>>6, wm = wave>>1, wn = wave&1;
  int sr = tid>>2, sc = (tid&3)*8;
  f32x4 acc[2][2] = {};
  for (int k0 = 0; k0 < K; k0 += 64) {
    __syncthreads();
    const bf16* ga = A + (size_t)(m0+sr)*K + k0 + sc;
    const bf16* gb = W + (size_t)(n0+sr)*K + k0 + sc;
    *(bf16x8*)&As[sr*72+sc]    = *(const bf16x8*)ga;
    *(bf16x8*)&As[sr*72+sc+32] = *(const bf16x8*)(ga+32);
    *(bf16x8*)&Bs[sr*72+sc]    = *(const bf16x8*)gb;
    *(bf16x8*)&Bs[sr*72+sc+32] = *(const bf16x8*)(gb+32);
    __syncthreads();
    #pragma unroll
    for (int kk=0;kk<2;kk++){
      bf16x8 af0 = *(const bf16x8*)&As[(wm*32+li)*72   +kk*32+quad*8];
      bf16x8 af1 = *(const bf16x8*)&As[(wm*32+16+li)*72+kk*32+quad*8];
      bf16x8 bf0 = *(const bf16x8*)&Bs[(wn*32+li)*72   +kk*32+quad*8];
      bf16x8 bf1 = *(const bf16x8*)&Bs[(wn*32+16+li)*72+kk*32+quad*8];
      acc[0][0]=MFMA16(af0,bf0,acc[0][0]);
      acc[0][1]=MFMA16(af0,bf1,acc[0][1]);
      acc[1][0]=MFMA16(af1,bf0,acc[1][0]);
      acc[1][1]=MFMA16(af1,bf1,acc[1][1]);
    }
  }
  #pragma unroll
  for (int i=0;i<2;i++)
  #pragma unroll
  for (int j=0;j<2;j++){
    int col = n0 + wn*32 + j*16 + li;
    float bv = (EPI==0) ? 0.0f : bias[col];
    #pragma unroll
    for (int r=0;r<4;r++){
      int row = m0 + wm*32 + i*16 + quad*4 + r;
      float v = acc[i][j][r] + bv;
      size_t off = (size_t)row*N + col;
      if (EPI==0)      { if (col < CC) v *= SCALE; outb[off] = (bf16)v; }
      else if (EPI==2) { v = 0.5f*v*(1.0f+erff(v*0.70710678118654752f)); outb[off] = (bf16)v; }
      else             { v += resf[off]; outf[off] = v; }
    }
  }
}

// ---------------- position-bias MLP (tiny) ----------------
__device__ __forceinline__ void ln6_relu(float* v, const float* w, const float* b){
  float mu=0;
  #pragma unroll
  for (int i=0;i<6;i++) mu += v[i];
  mu *= (1.0f/6.0f);
  float var=0;
  #pragma unroll
  for (int i=0;i<6;i++){ float d=v[i]-mu; var += d*d; }
  var *= (1.0f/6.0f);
  float rstd = rsqrtf(var + 1e-5f);
  #pragma unroll
  for (int i=0;i<6;i++){ float t=(v[i]-mu)*rstd*w[i]+b[i]; v[i] = t>0.f? t:0.f; }
}
__device__ __forceinline__ void fc66(const float* in, float* out, const float* w, const float* b){
  #pragma unroll
  for (int i=0;i<6;i++){
    float s=b[i];
    #pragma unroll
    for (int j=0;j<6;j++) s += in[j]*w[i*6+j];
    out[i]=s;
  }
}
__global__ __launch_bounds__(256) void pos_mlp_kernel(
    const float* pw, const float* pb, const float* l1w, const float* l1b,
    const float* f1w, const float* f1b, const float* l2w, const float* l2b,
    const float* f2w, const float* f2b, const float* l3w, const float* l3b,
    const float* f3w, const float* f3b, float* __restrict__ posb)
{
  int gid = blockIdx.x*256 + threadIdx.x;
  if (gid >= 2*2899) return;
  int br = gid / 2899, r = gid % 2899;
  int Hsp = br? 7:112, Wsp = br?112:7;
  int lpw = 2*Wsp-1;
  int iph = r / lpw, ipw = r % lpw;
  float c0 = (float)(iph - (Hsp-1)), c1 = (float)(ipw - (Wsp-1));
  float v[6], t[6];
  #pragma unroll
  for (int i=0;i<6;i++)
    v[i] = c0*pw[br*12+i*2] + c1*pw[br*12+i*2+1] + pb[br*6+i];
  ln6_relu(v, l1w+br*6, l1b+br*6); fc66(v, t, f1w+br*36, f1b+br*6);
  ln6_relu(t, l2w+br*6, l2b+br*6); fc66(t, v, f2w+br*36, f2b+br*6);
  ln6_relu(v, l3w+br*6, l3b+br*6);
  #pragma unroll
  for (int h=0;h<4;h++){
    float s=f3b[br*4+h];
    #pragma unroll
    for (int j=0;j<6;j++) s += v[j]*f3w[br*24+h*6+j];
    posb[(size_t)(br*2899 + r)*4 + h] = s;
  }
}

// ---------------- flash attention, one block per (br,b,window,head) ----------------
__device__ __forceinline__ int tok2l(int br, int t, int w) {
  if (br == 0) return (t/7)*WW + w*7 + (t - (t/7)*7);
  int th = t/112; return (w*7 + th)*WW + (t - th*112);
}
// relative-position code: a_t = h_t*lpw + w_t, exact for t < 784
__device__ __forceinline__ int acode(int br, int t) {
  int rh = br ? (((t>>4)*18725)>>17) : ((t*18725)>>17);
  return t + (br ? 111 : 6) * rh;
}

__global__ __launch_bounds__(512) void attn_kernel(const bf16* __restrict__ qkv,
    const float* __restrict__ posb, bf16* __restrict__ out)
{
  __shared__ __align__(16) bf16 Ks[832*40];    // [key 832][d 40], d>=24 zero
  __shared__ __align__(16) bf16 Vt[32*840];    // [d 32][key 840], row 24 = ones
  __shared__ __align__(16) bf16 Ps[8][32*72];  // per-wave P [i 32][key 72]
  __shared__ __align__(16) bf16 postab[2904];  // pos table for this (br,h)
  int bid = blockIdx.x;
  int br = bid & 1, h = (bid>>1)&3, w = (bid>>3)&15, b = bid>>7;
  int tid = threadIdx.x;
  int lane = tid&63, li = lane&15, quad = lane>>4, wave = tid>>6;
  size_t qbase = (size_t)b*LL*576;
  int coff = br*96 + h*24;
  // zero LDS (pads)
  for (int c = tid; c < (832*40)/8; c += 512) ((int4*)Ks)[c] = make_int4(0,0,0,0);
  for (int c = tid; c < (32*840)/8; c += 512) ((int4*)Vt)[c] = make_int4(0,0,0,0);
  __syncthreads();
  // stage K
  for (int c = tid; c < NT*3; c += 512) {
    int j = c/3, p = c - j*3;
    int l = tok2l(br, j, w);
    *(bf16x8*)&Ks[j*40 + p*8] =
        *(const bf16x8*)(qkv + qbase + (size_t)l*576 + 192 + coff + p*8);
  }
  // stage V transposed + ones row (softmax denominator via MFMA)
  for (int j = tid; j < NT; j += 512) {
    int l = tok2l(br, j, w);
    const bf16* src = qkv + qbase + (size_t)l*576 + 384 + coff;
    bf16x8 v0 = *(const bf16x8*)src;
    bf16x8 v1 = *(const bf16x8*)(src+8);
    bf16x8 v2 = *(const bf16x8*)(src+16);
    #pragma unroll
    for (int d=0; d<8; d++){
      Vt[d*840 + j]      = v0[d];
      Vt[(8+d)*840 + j]  = v1[d];
      Vt[(16+d)*840 + j] = v2[d];
    }
    Vt[24*840 + j] = (bf16)1.0f;
  }
  // stage pos table (bf16) for this (br,h)
  {
    const float* pb = posb + (size_t)br*2899*4 + h;
    for (int r = tid; r < 2904; r += 512)
      postab[r] = (bf16)(r < 2899 ? pb[(size_t)r*4] : 0.0f);
  }
  __syncthreads();

  for (int qg = wave; qg < 25; qg += 8) {      // 32 q-rows per group
    bf16x8 qf[2]; int ai2[2]; int iu[2];
    #pragma unroll
    for (int t=0;t<2;t++){
      iu[t] = qg*32 + t*16 + li;
      int ic = iu[t] < NT ? iu[t] : NT-1;
      int l = tok2l(br, ic, w);
      qf[t] = *(const bf16x8*)(qkv + qbase + (size_t)l*576 + coff + quad*8);
      ai2[t] = acode(br, ic);
    }
    f32x4 O[2][2] = {};
    for (int kc = 0; kc < 13; kc++) {          // 64 keys per chunk
      int kb = kc*64;
      // bias gathers from LDS pos table (overlap with MFMA below)
      float bb0[16], bb1[16];
      #pragma unroll
      for (int kt=0;kt<4;kt++)
        #pragma unroll
        for (int r=0;r<4;r++){
          int n = kt*4+r;
          int j = kb + kt*16 + quad*4 + r;
          int jc = j < NT ? j : NT-1;
          int aj = acode(br, jc);
          float b0 = (float)postab[ai2[0] - aj + 1449];
          float b1 = (float)postab[ai2[1] - aj + 1449];
          bb0[n] = j < NT ? b0 : -40.0f;
          bb1[n] = j < NT ? b1 : -40.0f;
        }
      bf16x8 kf[4];
      #pragma unroll
      for (int kt=0;kt<4;kt++)
        kf[kt] = *(const bf16x8*)&Ks[(kb + kt*16 + li)*40 + quad*8];
      f32x4 S0[4] = {{0,0,0,0},{0,0,0,0},{0,0,0,0},{0,0,0,0}};
      f32x4 S1[4] = {{0,0,0,0},{0,0,0,0},{0,0,0,0},{0,0,0,0}};
      #pragma unroll
      for (int kt=0;kt<4;kt++){
        S0[kt] = MFMA16(kf[kt], qf[0], S0[kt]);   // S^T = K*Q^T
        S1[kt] = MFMA16(kf[kt], qf[1], S1[kt]);
      }
      // P = exp(S + bias)  (no max subtraction: |S+bias| small, f32-safe)
      #pragma unroll
      for (int kt=0;kt<4;kt++){
        bf16x4 p0, p1;
        #pragma unroll
        for (int r=0;r<4;r++){
          p0[r] = (bf16)__expf(S0[kt][r] + bb0[kt*4+r]);
          p1[r] = (bf16)__expf(S1[kt][r] + bb1[kt*4+r]);
        }
        *(bf16x4*)&Ps[wave][li*72      + kt*16 + quad*4] = p0;
        *(bf16x4*)&Ps[wave][(16+li)*72 + kt*16 + quad*4] = p1;
      }
      asm volatile("s_waitcnt lgkmcnt(0)" ::: "memory");
      #pragma unroll
      for (int kk=0;kk<2;kk++){
        bf16x8 pf0 = *(const bf16x8*)&Ps[wave][li*72      + kk*32 + quad*8];
        bf16x8 pf1 = *(const bf16x8*)&Ps[wave][(16+li)*72 + kk*32 + quad*8];
        #pragma unroll
        for (int dt=0;dt<2;dt++){
          bf16x8 vf = *(const bf16x8*)&Vt[(dt*16+li)*840 + kb + kk*32 + quad*8];
          O[0][dt] = MFMA16(vf, pf0, O[0][dt]);       // O^T = Vt * P^T
          O[1][dt] = MFMA16(vf, pf1, O[1][dt]);
        }
      }
    }
    #pragma unroll
    for (int qt=0;qt<2;qt++){
      float lsum = __shfl(O[qt][1][0], 32+li, 64);    // ones-row (d=24) holds l_i
      float inv = 1.0f/lsum;
      int ii = iu[qt];
      if (ii < NT) {
        int l = tok2l(br, ii, w);
        bf16* dst = out + ((size_t)(b*LL + l))*CC + coff;
        #pragma unroll
        for (int dt=0;dt<2;dt++)
          #pragma unroll
          for (int r=0;r<4;r++){
            int d = dt*16 + quad*4 + r;
            if (d < 24) dst[d] = (bf16)(O[qt][dt][r]*inv);
          }
      }
    }
  }
}

// ---------------- host launcher ----------------
extern "C" void kernel_launch(void* const* d_in, const int* in_sizes, int n_in,
                              void* d_out, int out_size, void* d_ws, size_t ws_size,
                              hipStream_t stream)
{
  const float* x    = (const float*)d_in[0];
  const float* n1w  = (const float*)d_in[1];
  const float* n1b  = (const float*)d_in[2];
  const float* qkvw = (const float*)d_in[3];
  const float* pjw  = (const float*)d_in[4];
  const float* pjb  = (const float*)d_in[5];
  const float* n2w  = (const float*)d_in[6];
  const float* n2b  = (const float*)d_in[7];
  const float* f1w  = (const float*)d_in[8];
  const float* f1b  = (const float*)d_in[9];
  const float* f2w  = (const float*)d_in[10];
  const float* f2b  = (const float*)d_in[11];

  char* p = (char*)d_ws;
  auto alloc = [&](size_t bytes){ void* r = (void*)p; p += (bytes + 255) & ~(size_t)255; return r; };
  bf16*  img  = (bf16*) alloc((size_t)25088*192*2);
  bf16*  qkvb = (bf16*) alloc((size_t)25088*576*2);
  bf16*  attn = (bf16*) alloc((size_t)25088*192*2);
  float* x2   = (float*)alloc((size_t)25088*192*4);
  bf16*  y    = (bf16*) alloc((size_t)25088*192*2);
  bf16*  hbuf = (bf16*) alloc((size_t)25088*768*2);
  float* posb = (float*)alloc((size_t)2*2899*4*4);
  bf16*  qkvw_b = (bf16*)alloc((size_t)576*192*2);
  bf16*  pjw_b  = (bf16*)alloc((size_t)192*192*2);
  bf16*  f1w_b  = (bf16*)alloc((size_t)768*192*2);
  bf16*  f2w_b  = (bf16*)alloc((size_t)192*768*2);
  float* outp = (float*)d_out;

  cvt_kernel<<<108,256,0,stream>>>(qkvw, qkvw_b, 576*192);
  cvt_kernel<<<36, 256,0,stream>>>(pjw,  pjw_b,  192*192);
  cvt_kernel<<<144,256,0,stream>>>(f1w,  f1w_b,  768*192);
  cvt_kernel<<<144,256,0,stream>>>(f2w,  f2w_b,  192*768);

  ln_kernel<<<6272,256,0,stream>>>(x, n1w, n1b, img);
  gemm_kernel<0><<<dim3(392,9),256,0,stream>>>(img, qkvw_b, 192, 576,
      nullptr, nullptr, qkvb, nullptr);
  pos_mlp_kernel<<<23,256,0,stream>>>(
      (const float*)d_in[12], (const float*)d_in[13], (const float*)d_in[14],
      (const float*)d_in[15], (const float*)d_in[16], (const float*)d_in[17],
      (const float*)d_in[18], (const float*)d_in[19], (const float*)d_in[20],
      (const float*)d_in[21], (const float*)d_in[22], (const float*)d_in[23],
      (const float*)d_in[24], (const float*)d_in[25], posb);
  attn_kernel<<<256,512,0,stream>>>(qkvb, posb, attn);
  gemm_kernel<1><<<dim3(392,3),256,0,stream>>>(attn, pjw_b, 192, 192,
      pjb, x, nullptr, x2);
  ln_kernel<<<6272,256,0,stream>>>(x2, n2w, n2b, y);
  gemm_kernel<2><<<dim3(392,12),256,0,stream>>>(y, f1w_b, 192, 768,
      f1b, nullptr, hbuf, nullptr);
  gemm_kernel<3><<<dim3(392,3),256,0,stream>>>(hbuf, f2w_b, 768, 192,
      f2b, x2, nullptr, outp);
}